// Round 11
// baseline (11103.583 us; speedup 1.0000x reference)
//
// ODE-RNN (B=128, F=512, I=128, H=512, O=1) on MI355X — Round 11.
// R10 (per-wave flags) REGRESSED (7.3 vs R9 4.78 ms; WRITE_SIZE 4x = flag
// thrash). Third confirmation that signal-path tweaks don't move the ~4.5K
// cy/stage latency floor. R11 hides it structurally: each block runs TWO
// independent 32-sample chains (groups 2c, 2c+1) sharing the SAME weight
// registers. Body: computeA, signalA, computeB, signalB, (x@Wih for both),
// waitA, waitB — chain B's compute fills chain A's poll window; both chains
// advance one stage per body => per-chain period ~ (R9 + ~800cy)/2.
// Signaling/polling/exchange mechanics are VERBATIM R9 (proven exact):
// per-wave vmcnt(0) drain -> __syncthreads -> tid0 plain volatile block flag;
// consumers poll 16 flags with buffer_inv+plain loads; direct frag-order L2
// exchange, no LDS. 2 cohorts x 16 blocks (32 working CUs).
// Predicted: 2.5-3.5 ms; WRITE_SIZE ~5.4 MB; absmax ~0.

#include <hip/hip_runtime.h>
#include <hip/hip_bf16.h>
#include <cstdint>
#include <cstddef>

#define HD 512
#define ID 128
#define FF 512
#define G 4          // groups of 32 samples (2 per superblock-cohort)
#define S 32         // samples per group
#define NBLK 16      // blocks per cohort (32-col weight shards)
#define NSUPER 2     // cohorts; cohort c runs groups {2c, 2c+1}
#define NLAUNCH 256  // blocks launched (>= 9 complete cohorts by pigeonhole)

// ctl word offsets (all zeroed before seq_kernel)
#define CT_TICKET 0          // [16] per-XCD ticket counters
#define CT_CLAIM 16          // cohort claim counter
#define CT_TOTAL 17          // registered-block counter
#define CT_MAP 20            // [256] cohort-slot -> claim+1 (0 = unclaimed)
#define CT_PFLAG 512         // [G][64] per-block stage flags, 256B/group
#define CT_WORDS (512 + G * 64)

#define XFRAG_ELEMS ((size_t)FF * 8 * 4 * 64 * 8)   // 8,388,608 bf16

typedef __bf16 bf16x8_t __attribute__((ext_vector_type(8)));
typedef unsigned short ushort8_t __attribute__((ext_vector_type(8)));
typedef unsigned short ushort4_t __attribute__((ext_vector_type(4)));
typedef float f32x4_t __attribute__((ext_vector_type(4)));

__device__ __forceinline__ unsigned short f2b(float x) {
  __hip_bfloat16 h = __float2bfloat16(x);
  return *reinterpret_cast<unsigned short*>(&h);
}
__device__ __forceinline__ bf16x8_t ld_frag(const unsigned short* p) {
  ushort8_t u = *reinterpret_cast<const ushort8_t*>(p);
  return __builtin_bit_cast(bf16x8_t, u);
}

// --- fp32 -> bf16 fragment-order weight pack (same layout as R3-R10) -------
__global__ void pack_kernel(const float* __restrict__ in,
                            unsigned short* __restrict__ out, int Kd) {
  int i = blockIdx.x * blockDim.x + threadIdx.x;
  int total = HD * Kd;
  if (i >= total) return;
  int KT = Kd >> 5;
  int j = i & 7;
  int lane = (i >> 3) & 63;
  int t = i >> 9;
  int kt = t % KT;
  int colt = t / KT;
  int n = lane & 15, kq = lane >> 4;
  out[i] = f2b(in[(size_t)(colt * 16 + n) * Kd + kt * 32 + kq * 8 + j]);
}

// --- x -> bf16 B-fragment order: xf[f][st=b>>4][kt<4][lane=n+16kq][8] ------
__global__ void xpack_kernel(const float* __restrict__ in,
                             unsigned short* __restrict__ out) {
  size_t i = (size_t)blockIdx.x * blockDim.x + threadIdx.x;
  if (i >= XFRAG_ELEMS) return;
  int e = (int)(i & 7);
  int lane = (int)((i >> 3) & 63);
  int kt = (int)((i >> 9) & 3);
  int st = (int)((i >> 11) & 7);
  int f = (int)(i >> 14);
  int n = lane & 15, kq = lane >> 4;
  int b = st * 16 + n;
  int ii = kt * 32 + kq * 8 + e;
  out[i] = f2b(in[((size_t)b * FF + f) * ID + ii]);
}

// --- dt table: dtp[f*128 + b] = tp[b][f] - tp[b][f-1] (0 at f=0) -----------
__global__ void dtpack_kernel(const float* __restrict__ tp,
                              float* __restrict__ dtp) {
  int i = blockIdx.x * blockDim.x + threadIdx.x;
  if (i >= FF * 128) return;
  int f = i >> 7, b = i & 127;
  dtp[i] = (f > 0) ? (tp[(size_t)b * FF + f] - tp[(size_t)b * FF + f - 1])
                   : 0.f;
}

__global__ void zero_kernel(unsigned int* __restrict__ p, int n) {
  int i = blockIdx.x * blockDim.x + threadIdx.x;
  if (i < n) p[i] = 0u;
}

// Two interleaved 8-chains over kt=0..15; acc-in carried on even chain.
// base: ushort8 array over [32 rows][64 lanes]; rows = rt*16 + kt.
__device__ __forceinline__ f32x4_t mm16g(const bf16x8_t* wf,
                                         const ushort8_t* base, int row0,
                                         int lane, f32x4_t acc) {
  f32x4_t acc1 = {0.f, 0.f, 0.f, 0.f};
#pragma unroll
  for (int kt = 0; kt < 16; kt += 2) {
    bf16x8_t a0 = __builtin_bit_cast(bf16x8_t, base[(row0 + kt) * 64 + lane]);
    bf16x8_t a1 = __builtin_bit_cast(bf16x8_t, base[(row0 + kt + 1) * 64 + lane]);
    acc  = __builtin_amdgcn_mfma_f32_16x16x32_bf16(wf[kt], a0, acc, 0, 0, 0);
    acc1 = __builtin_amdgcn_mfma_f32_16x16x32_bf16(wf[kt + 1], a1, acc1, 0, 0, 0);
  }
  acc[0] += acc1[0]; acc[1] += acc1[1]; acc[2] += acc1[2]; acc[3] += acc1[3];
  return acc;
}

// --- the sequential recurrence ---------------------------------------------
__global__ __launch_bounds__(256, 1) void seq_kernel(
    const float* __restrict__ dtp,
    const float* __restrict__ b1, const float* __restrict__ b2,
    const float* __restrict__ bih, const float* __restrict__ bhh,
    const float* __restrict__ Wc,
    const unsigned short* __restrict__ W1p, const unsigned short* __restrict__ W2p,
    const unsigned short* __restrict__ Whhp, const unsigned short* __restrict__ Wihp,
    const unsigned short* __restrict__ xf,
    unsigned short* __restrict__ actg,   // G * 2 * S*512 bf16, frag order
    unsigned int* __restrict__ ctl,      // control words (see CT_*)
    float* __restrict__ logits) {        // 128 fp32, pre-zeroed
  __shared__ float redl[S][2];
  __shared__ int role[2];

  const int tid = threadIdx.x;

  // ---- XCD-aware registration & cohort claiming (tid 0; R5-R10 proven) ----
  if (tid == 0) {
    unsigned xcc;
    asm volatile("s_getreg_b32 %0, hwreg(HW_REG_XCC_ID, 0, 32)" : "=s"(xcc));
    const int xcd = (int)(xcc & 15u);
    unsigned rank = __hip_atomic_fetch_add(&ctl[CT_TICKET + xcd], 1u,
                                           __ATOMIC_RELAXED,
                                           __HIP_MEMORY_SCOPE_AGENT);
    const unsigned slot = (unsigned)xcd * 16u + (rank >> 4);
    if ((rank & 15u) == 15u) {  // cohort completer claims a cohort id
      unsigned gg = __hip_atomic_fetch_add(&ctl[CT_CLAIM], 1u,
                                           __ATOMIC_RELAXED,
                                           __HIP_MEMORY_SCOPE_AGENT);
      __hip_atomic_store(&ctl[CT_MAP + slot], gg + 1u, __ATOMIC_RELAXED,
                         __HIP_MEMORY_SCOPE_AGENT);
      asm volatile("s_waitcnt vmcnt(0)" ::: "memory");  // publish before total
    }
    __hip_atomic_fetch_add(&ctl[CT_TOTAL], 1u, __ATOMIC_RELAXED,
                           __HIP_MEMORY_SCOPE_AGENT);
    unsigned m;
    for (;;) {
      m = __hip_atomic_load(&ctl[CT_MAP + slot], __ATOMIC_RELAXED,
                            __HIP_MEMORY_SCOPE_AGENT);
      if (m) break;
      if (__hip_atomic_load(&ctl[CT_TOTAL], __ATOMIC_RELAXED,
                            __HIP_MEMORY_SCOPE_AGENT) >= (unsigned)NLAUNCH) {
        m = __hip_atomic_load(&ctl[CT_MAP + slot], __ATOMIC_RELAXED,
                              __HIP_MEMORY_SCOPE_AGENT);
        break;
      }
      __builtin_amdgcn_s_sleep(2);
    }
    role[0] = (m == 0 || m > (unsigned)NSUPER) ? -1 : (int)(m - 1);
    role[1] = (int)(rank & 15u);
  }
  __syncthreads();
  if (role[0] < 0) return;   // surplus / incomplete cohort: exit
  const int sg = role[0];    // cohort 0..1 — runs groups {2sg, 2sg+1}
  const int j = role[1];     // 32-col weight shard 0..15

  const int wave = tid >> 6;
  const int lane = tid & 63;
  const int n = lane & 15;
  const int kq = lane >> 4;
  const int ct = wave & 1;         // col-tile within shard
  const int rt = wave >> 1;        // row-tile (samples)
  const int colt = j * 2 + ct;     // global 16-col tile
  const int sl2 = rt * 16 + n;     // this lane's sample (D col = lane&15)
  const int gc0 = j * 32 + ct * 16 + kq * 4;  // lane's 4-col base (D rows)

  // ---- weights into registers (shared by both chains) ----
  bf16x8_t w1f[16], w2f[16], whhf[16], wihf[4];
#pragma unroll
  for (int kt = 0; kt < 16; ++kt) {
    w1f[kt]  = ld_frag(W1p  + (size_t)(colt * 16 + kt) * 512 + lane * 8);
    w2f[kt]  = ld_frag(W2p  + (size_t)(colt * 16 + kt) * 512 + lane * 8);
    whhf[kt] = ld_frag(Whhp + (size_t)(colt * 16 + kt) * 512 + lane * 8);
  }
#pragma unroll
  for (int kt = 0; kt < 4; ++kt)
    wihf[kt] = ld_frag(Wihp + (size_t)(colt * 4 + kt) * 512 + lane * 8);

  const f32x4_t b1v = *reinterpret_cast<const f32x4_t*>(&b1[gc0]);
  const f32x4_t b2v = *reinterpret_cast<const f32x4_t*>(&b2[gc0]);
  f32x4_t bbv;
#pragma unroll
  for (int r_ = 0; r_ < 4; ++r_) bbv[r_] = bih[gc0 + r_] + bhh[gc0 + r_];

  // per-chain lane-private state
  f32x4_t hv[2], fsv[2];
#pragma unroll
  for (int cc = 0; cc < 2; ++cc) {
    hv[cc] = (f32x4_t){0.f, 0.f, 0.f, 0.f};
    fsv[cc] = (f32x4_t){0.f, 0.f, 0.f, 0.f};
  }
  unsigned short* actp[2];
  unsigned int* pfp[2];
  int s0c[2];
#pragma unroll
  for (int cc = 0; cc < 2; ++cc) {
    const int g = sg * 2 + cc;
    actp[cc] = actg + (size_t)g * (2 * S * 512);
    pfp[cc] = &ctl[CT_PFLAG + g * 64];   // 16 words, own 256B
    s0c[cc] = g * S;
  }
  int bar = 0;

  // Producer store offset (elems) in consumer B-frag order (R9-proven).
  const size_t soff =
      ((size_t)(rt * 16 + j) * 64 + n + 16 * (2 * ct + (kq >> 1))) * 8 +
      (kq & 1) * 4;
  const int row0 = rt * 16;

  asm volatile("buffer_inv" ::: "memory");   // drop any pre-kernel L1 lines
  asm volatile("s_waitcnt vmcnt(0)" ::: "memory");

  // signal (R9-verbatim, per chain): all waves drain own stores to local L2,
  // block barrier, tid0 plain volatile flag store.
  auto signal = [&](unsigned int* pf) {
    asm volatile("s_waitcnt vmcnt(0)" ::: "memory");
    __syncthreads();
    if (tid == 0)
      *(volatile unsigned int*)(pf + j) = (unsigned)(bar + 1);
  };
  // wait (R9-verbatim): poll 16 block-flags, buffer_inv each iter; the final
  // inv precedes the subsequent frag loads (no stale L1).
  auto wait_ = [&](unsigned int* pf) {
    const unsigned want = (unsigned)(bar + 1);
    for (;;) {
      asm volatile("buffer_inv" ::: "memory");
      unsigned v = *(volatile const unsigned int*)(pf + (lane & 15));
      if (__ballot(v < want) == 0ull) break;
    }
  };

#pragma unroll 1
  for (int f = 0; f < FF; ++f) {
    float dsc[2];
#pragma unroll
    for (int cc = 0; cc < 2; ++cc) dsc[cc] = dtp[f * 128 + s0c[cc] + sl2];

    // ---- A: g1 = relu(h @ W1^T + b1) ----
#pragma unroll
    for (int cc = 0; cc < 2; ++cc) {
      const ushort8_t* src =
          (const ushort8_t*)(actp[cc] + (size_t)((bar & 1) ^ 1) * (S * 512));
      f32x4_t acc = {0.f, 0.f, 0.f, 0.f};
      acc = mm16g(w1f, src, row0, lane, acc);
      unsigned short* dst = actp[cc] + (size_t)(bar & 1) * (S * 512);
      ushort4_t o;
#pragma unroll
      for (int r_ = 0; r_ < 4; ++r_) {
        float y = acc[r_] + b1v[r_];
        o[r_] = f2b(y > 0.f ? y : 0.f);
      }
      *reinterpret_cast<ushort4_t*>(dst + soff) = o;
      signal(pfp[cc]);
    }
    wait_(pfp[0]); wait_(pfp[1]); ++bar;

    // ---- B: k1 = g1 @ W2^T + b2; publish h+0.8dt k1; hv += 0.5dt k1 ----
#pragma unroll
    for (int cc = 0; cc < 2; ++cc) {
      const ushort8_t* src =
          (const ushort8_t*)(actp[cc] + (size_t)((bar & 1) ^ 1) * (S * 512));
      f32x4_t acc = {0.f, 0.f, 0.f, 0.f};
      acc = mm16g(w2f, src, row0, lane, acc);
      unsigned short* dst = actp[cc] + (size_t)(bar & 1) * (S * 512);
      ushort4_t o;
#pragma unroll
      for (int r_ = 0; r_ < 4; ++r_) {
        float k1 = acc[r_] + b2v[r_];
        float ho = hv[cc][r_];
        o[r_] = f2b(ho + 0.8f * dsc[cc] * k1);
        hv[cc][r_] = ho + 0.5f * dsc[cc] * k1;
      }
      *reinterpret_cast<ushort4_t*>(dst + soff) = o;
      signal(pfp[cc]);
    }
    wait_(pfp[0]); wait_(pfp[1]); ++bar;

    // ---- C: g2 = relu(h2 @ W1^T + b1) ----
#pragma unroll
    for (int cc = 0; cc < 2; ++cc) {
      const ushort8_t* src =
          (const ushort8_t*)(actp[cc] + (size_t)((bar & 1) ^ 1) * (S * 512));
      f32x4_t acc = {0.f, 0.f, 0.f, 0.f};
      acc = mm16g(w1f, src, row0, lane, acc);
      unsigned short* dst = actp[cc] + (size_t)(bar & 1) * (S * 512);
      ushort4_t o;
#pragma unroll
      for (int r_ = 0; r_ < 4; ++r_) {
        float y = acc[r_] + b1v[r_];
        o[r_] = f2b(y > 0.f ? y : 0.f);
      }
      *reinterpret_cast<ushort4_t*>(dst + soff) = o;
      signal(pfp[cc]);
    }
    wait_(pfp[0]); wait_(pfp[1]); ++bar;

    // ---- D: k2 = g2 @ W2^T + b2; h' = hv + 0.5dt k2; publish h' ----
    f32x4_t accx[2];
#pragma unroll
    for (int cc = 0; cc < 2; ++cc) {
      const ushort8_t* src =
          (const ushort8_t*)(actp[cc] + (size_t)((bar & 1) ^ 1) * (S * 512));
      f32x4_t acc = {0.f, 0.f, 0.f, 0.f};
      acc = mm16g(w2f, src, row0, lane, acc);
      unsigned short* dst = actp[cc] + (size_t)(bar & 1) * (S * 512);
      ushort4_t o;
#pragma unroll
      for (int r_ = 0; r_ < 4; ++r_) {
        float h = hv[cc][r_] + 0.5f * dsc[cc] * (acc[r_] + b2v[r_]);
        hv[cc][r_] = h;
        o[r_] = f2b(h);
      }
      *reinterpret_cast<ushort4_t*>(dst + soff) = o;
      signal(pfp[cc]);
    }
    // x @ Wih^T for both chains between signals and waits (fills poll time).
#pragma unroll
    for (int cc = 0; cc < 2; ++cc) {
      const ushort8_t* xsrc =
          (const ushort8_t*)xf +
          (size_t)((f * 8 + (sg * 2 + cc) * 2 + rt) * 4) * 64;
      accx[cc] = (f32x4_t){0.f, 0.f, 0.f, 0.f};
#pragma unroll
      for (int kt = 0; kt < 4; ++kt) {
        bf16x8_t a = __builtin_bit_cast(bf16x8_t, xsrc[kt * 64 + lane]);
        accx[cc] = __builtin_amdgcn_mfma_f32_16x16x32_bf16(wihf[kt], a,
                                                           accx[cc], 0, 0, 0);
      }
    }
    wait_(pfp[0]); wait_(pfp[1]); ++bar;

    // ---- RNN: h = tanh(x@Wih^T + h' @ Whh^T + bih + bhh) ----
#pragma unroll
    for (int cc = 0; cc < 2; ++cc) {
      const ushort8_t* src =
          (const ushort8_t*)(actp[cc] + (size_t)((bar & 1) ^ 1) * (S * 512));
      f32x4_t acc = mm16g(whhf, src, row0, lane, accx[cc]);
      unsigned short* dst = actp[cc] + (size_t)(bar & 1) * (S * 512);
      ushort4_t o;
#pragma unroll
      for (int r_ = 0; r_ < 4; ++r_) {
        float t = tanhf(acc[r_] + bbv[r_]);
        hv[cc][r_] = t;
        fsv[cc][r_] += t;
        o[r_] = f2b(t);
      }
      *reinterpret_cast<ushort4_t*>(dst + soff) = o;
      signal(pfp[cc]);
    }
    wait_(pfp[0]); wait_(pfp[1]); ++bar;
  }

  // ---- classifier: per chain, logits[s] += sum over this block's 32 cols --
#pragma unroll 1
  for (int cc = 0; cc < 2; ++cc) {
    float p = fsv[cc][0] * Wc[gc0] + fsv[cc][1] * Wc[gc0 + 1] +
              fsv[cc][2] * Wc[gc0 + 2] + fsv[cc][3] * Wc[gc0 + 3];
    p += __shfl_xor(p, 16, 64);   // reduce over kq
    p += __shfl_xor(p, 32, 64);
    if (lane < 16) redl[rt * 16 + lane][ct] = p;
    __syncthreads();
    if (tid < S) {
      float v = redl[tid][0] + redl[tid][1];
      atomicAdd(&logits[s0c[cc] + tid], v);   // device-scope, cross-XCD safe
    }
    __syncthreads();
  }
}

__global__ void fin_kernel(const float* __restrict__ logits,
                           const float* __restrict__ bc,
                           float* __restrict__ out) {
  int b = threadIdx.x;
  if (b < 128) out[b] = 1.f / (1.f + __expf(-(logits[b] * (1.f / FF) + bc[0])));
}

// --- launch -----------------------------------------------------------------
extern "C" void kernel_launch(void* const* d_in, const int* in_sizes, int n_in,
                              void* d_out, int out_size, void* d_ws, size_t ws_size,
                              hipStream_t stream) {
  const float* x   = (const float*)d_in[0];
  const float* tp  = (const float*)d_in[1];
  const float* W1  = (const float*)d_in[2];
  const float* b1  = (const float*)d_in[3];
  const float* W2  = (const float*)d_in[4];
  const float* b2  = (const float*)d_in[5];
  const float* Wih = (const float*)d_in[6];
  const float* Whh = (const float*)d_in[7];
  const float* bih = (const float*)d_in[8];
  const float* bhh = (const float*)d_in[9];
  const float* Wc  = (const float*)d_in[10];
  const float* bc  = (const float*)d_in[11];
  float* out = (float*)d_out;

  unsigned short* W1p  = (unsigned short*)d_ws;
  unsigned short* W2p  = W1p + (size_t)HD * HD;
  unsigned short* Whhp = W2p + (size_t)HD * HD;
  unsigned short* Wihp = Whhp + (size_t)HD * HD;
  unsigned short* xfp  = Wihp + (size_t)HD * ID;
  float*          dtp  = (float*)(xfp + XFRAG_ELEMS);
  unsigned short* actg = (unsigned short*)(dtp + FF * 128);  // G*2*S*512 bf16
  unsigned int*   ctl  = (unsigned int*)(actg + (size_t)G * 2 * S * 512);
  float*          logits = (float*)(ctl + CT_WORDS);
  // total ws use ~19.1 MB

  pack_kernel<<<(HD * HD + 255) / 256, 256, 0, stream>>>(W1, W1p, HD);
  pack_kernel<<<(HD * HD + 255) / 256, 256, 0, stream>>>(W2, W2p, HD);
  pack_kernel<<<(HD * HD + 255) / 256, 256, 0, stream>>>(Whh, Whhp, HD);
  pack_kernel<<<(HD * ID + 255) / 256, 256, 0, stream>>>(Wih, Wihp, ID);
  xpack_kernel<<<(int)((XFRAG_ELEMS + 255) / 256), 256, 0, stream>>>(x, xfp);
  dtpack_kernel<<<(FF * 128 + 255) / 256, 256, 0, stream>>>(tp, dtp);
  // zero actg (h0 = 0 read at f=0, both parities) + ctl + logits (contiguous)
  int nz = (int)(G * 2 * S * 512 / 2) + CT_WORDS + 128;
  zero_kernel<<<(nz + 255) / 256, 256, 0, stream>>>((unsigned int*)actg, nz);

  seq_kernel<<<dim3(NLAUNCH), dim3(256), 0, stream>>>(
      dtp, b1, b2, bih, bhh, Wc, W1p, W2p, Whhp, Wihp, xfp, actg, ctl, logits);
  fin_kernel<<<dim3(1), dim3(128), 0, stream>>>(logits, bc, out);
}

// Round 12
// 3513.020 us; speedup vs baseline: 3.1607x; 3.1607x over previous
//
// ODE-RNN (B=128, F=512, I=128, H=512, O=1) on MI355X — Round 12.
// R9 = champion (4.78 ms, 2560 stages x ~4480 cy). R10/R11 proved the
// per-stage latency window (~3900 cy) resists mechanism tweaks and naive
// chain-interleave. R12 shrinks the COUNT: associativity folding with
// precomputed W12=W1*W2, Whh2=Whh*W2, c1=W1*b2, cw=Whh*b2 gives 3
// exchanges/f instead of 5 (hp is only consumed as hp@Whh^T):
//   S1: xchg h  -> z1=h@W1^T+b1 (crit); publish relu(z1); defer u=h@Whh^T
//   S2: xchg g1 -> z2=z1+0.8dt(g1@W12^T+c1); publish relu(z2);
//                  defer w1=g1@Whh2^T
//   S3: xchg g2 -> w2=g2@Whh2^T; h'=tanh(x@Wih^T+u+0.5dt(w1+w2)+dt*cw+bb);
//                  publish h'; defer x@Wih^T(f+1)
// Same MFMA count (84/f), same RK2 trajectory exactly; z1 now carried fp32
// (more accurate than R9). Deferred matmuls reuse the SAME loaded frag regs
// inside the poll window. All exchange mechanics verbatim R9 (proven exact).
// Predicted: 2.7-3.6 ms; absmax <= 2e-3 (bf16 W12/Whh2, dt-scaled).

#include <hip/hip_runtime.h>
#include <hip/hip_bf16.h>
#include <cstdint>
#include <cstddef>

#define HD 512
#define ID 128
#define FF 512
#define G 4          // groups (each owns 32 samples)
#define S 32         // samples per group
#define NBLK 16      // blocks per group (32-col weight shards)
#define NLAUNCH 256  // blocks launched (>= 9 complete cohorts by pigeonhole)

// ctl word offsets (all zeroed before seq_kernel)
#define CT_TICKET 0          // [16] per-XCD ticket counters
#define CT_CLAIM 16          // group claim counter
#define CT_TOTAL 17          // registered-block counter
#define CT_MAP 20            // [256] cohort -> group+1 (0 = unclaimed)
#define CT_PFLAG 512         // [G][64] per-block stage flags, 256B/group
#define CT_WORDS (512 + G * 64)

#define XFRAG_ELEMS ((size_t)FF * 8 * 4 * 64 * 8)   // 8,388,608 bf16

typedef __bf16 bf16x8_t __attribute__((ext_vector_type(8)));
typedef unsigned short ushort8_t __attribute__((ext_vector_type(8)));
typedef unsigned short ushort4_t __attribute__((ext_vector_type(4)));
typedef float f32x4_t __attribute__((ext_vector_type(4)));

__device__ __forceinline__ unsigned short f2b(float x) {
  __hip_bfloat16 h = __float2bfloat16(x);
  return *reinterpret_cast<unsigned short*>(&h);
}
__device__ __forceinline__ bf16x8_t ld_frag(const unsigned short* p) {
  ushort8_t u = *reinterpret_cast<const ushort8_t*>(p);
  return __builtin_bit_cast(bf16x8_t, u);
}

// --- fp32 -> bf16 fragment-order weight pack (same layout as R3-R11) -------
__global__ void pack_kernel(const float* __restrict__ in,
                            unsigned short* __restrict__ out, int Kd) {
  int i = blockIdx.x * blockDim.x + threadIdx.x;
  int total = HD * Kd;
  if (i >= total) return;
  int KT = Kd >> 5;
  int j = i & 7;
  int lane = (i >> 3) & 63;
  int t = i >> 9;
  int kt = t % KT;
  int colt = t / KT;
  int n = lane & 15, kq = lane >> 4;
  out[i] = f2b(in[(size_t)(colt * 16 + n) * Kd + kt * 32 + kq * 8 + j]);
}

// --- C = A * B (512x512 fp32 row-major), naive-but-adequate (~tens of us) --
__global__ void mm512_kernel(const float* __restrict__ A,
                             const float* __restrict__ B,
                             float* __restrict__ C) {
  const int i = blockIdx.x;          // row
  const int j0 = threadIdx.x;        // col (and col+256)
  float acc0 = 0.f, acc1 = 0.f;
#pragma unroll 8
  for (int k = 0; k < 512; ++k) {
    float a = A[i * 512 + k];
    acc0 += a * B[k * 512 + j0];
    acc1 += a * B[k * 512 + j0 + 256];
  }
  C[i * 512 + j0] = acc0;
  C[i * 512 + j0 + 256] = acc1;
}

// --- out = W (512x512) * v (512) ------------------------------------------
__global__ void mv_kernel(const float* __restrict__ W,
                          const float* __restrict__ v,
                          float* __restrict__ out) {
  int i = blockIdx.x * blockDim.x + threadIdx.x;
  if (i >= 512) return;
  float s = 0.f;
#pragma unroll 8
  for (int k = 0; k < 512; ++k) s += W[(size_t)i * 512 + k] * v[k];
  out[i] = s;
}

// --- x -> bf16 B-fragment order: xf[f][st=b>>4][kt<4][lane=n+16kq][8] ------
__global__ void xpack_kernel(const float* __restrict__ in,
                             unsigned short* __restrict__ out) {
  size_t i = (size_t)blockIdx.x * blockDim.x + threadIdx.x;
  if (i >= XFRAG_ELEMS) return;
  int e = (int)(i & 7);
  int lane = (int)((i >> 3) & 63);
  int kt = (int)((i >> 9) & 3);
  int st = (int)((i >> 11) & 7);
  int f = (int)(i >> 14);
  int n = lane & 15, kq = lane >> 4;
  int b = st * 16 + n;
  int ii = kt * 32 + kq * 8 + e;
  out[i] = f2b(in[((size_t)b * FF + f) * ID + ii]);
}

// --- dt table: dtp[f*128 + b] = tp[b][f] - tp[b][f-1] (0 at f=0) -----------
__global__ void dtpack_kernel(const float* __restrict__ tp,
                              float* __restrict__ dtp) {
  int i = blockIdx.x * blockDim.x + threadIdx.x;
  if (i >= FF * 128) return;
  int f = i >> 7, b = i & 127;
  dtp[i] = (f > 0) ? (tp[(size_t)b * FF + f] - tp[(size_t)b * FF + f - 1])
                   : 0.f;
}

__global__ void zero_kernel(unsigned int* __restrict__ p, int n) {
  int i = blockIdx.x * blockDim.x + threadIdx.x;
  if (i < n) p[i] = 0u;
}

// Load the 16 activation frags of this wave's K-slab into registers.
__device__ __forceinline__ void ld16(const ushort8_t* base, int row0,
                                     int lane, bf16x8_t a[16]) {
#pragma unroll
  for (int kt = 0; kt < 16; ++kt)
    a[kt] = __builtin_bit_cast(bf16x8_t, base[(row0 + kt) * 64 + lane]);
}
// acc += W-shard @ act using preloaded frags; two interleaved 8-chains.
__device__ __forceinline__ f32x4_t mm16r(const bf16x8_t* wf,
                                         const bf16x8_t a[16], f32x4_t acc) {
  f32x4_t acc1 = {0.f, 0.f, 0.f, 0.f};
#pragma unroll
  for (int kt = 0; kt < 16; kt += 2) {
    acc  = __builtin_amdgcn_mfma_f32_16x16x32_bf16(wf[kt], a[kt], acc, 0, 0, 0);
    acc1 = __builtin_amdgcn_mfma_f32_16x16x32_bf16(wf[kt + 1], a[kt + 1], acc1,
                                                   0, 0, 0);
  }
  acc[0] += acc1[0]; acc[1] += acc1[1]; acc[2] += acc1[2]; acc[3] += acc1[3];
  return acc;
}

// --- the sequential recurrence ---------------------------------------------
__global__ __launch_bounds__(256, 1) void seq_kernel(
    const float* __restrict__ dtp,
    const float* __restrict__ b1, const float* __restrict__ c1,
    const float* __restrict__ cw,
    const float* __restrict__ bih, const float* __restrict__ bhh,
    const float* __restrict__ Wc,
    const unsigned short* __restrict__ W1p,
    const unsigned short* __restrict__ Whhp,
    const unsigned short* __restrict__ W12p,
    const unsigned short* __restrict__ Whh2p,
    const unsigned short* __restrict__ Wihp,
    const unsigned short* __restrict__ xf,
    unsigned short* __restrict__ actg,   // G * 2 * S*512 bf16, frag order
    unsigned int* __restrict__ ctl,      // control words (see CT_*)
    float* __restrict__ logits) {        // 128 fp32, pre-zeroed
  __shared__ float redl[S][2];
  __shared__ int role[2];

  const int tid = threadIdx.x;

  // ---- XCD-aware registration & group claiming (tid 0; R5-R11 proven) -----
  if (tid == 0) {
    unsigned xcc;
    asm volatile("s_getreg_b32 %0, hwreg(HW_REG_XCC_ID, 0, 32)" : "=s"(xcc));
    const int xcd = (int)(xcc & 15u);
    unsigned rank = __hip_atomic_fetch_add(&ctl[CT_TICKET + xcd], 1u,
                                           __ATOMIC_RELAXED,
                                           __HIP_MEMORY_SCOPE_AGENT);
    const unsigned slot = (unsigned)xcd * 16u + (rank >> 4);
    if ((rank & 15u) == 15u) {  // cohort completer claims a group id
      unsigned gg = __hip_atomic_fetch_add(&ctl[CT_CLAIM], 1u,
                                           __ATOMIC_RELAXED,
                                           __HIP_MEMORY_SCOPE_AGENT);
      __hip_atomic_store(&ctl[CT_MAP + slot], gg + 1u, __ATOMIC_RELAXED,
                         __HIP_MEMORY_SCOPE_AGENT);
      asm volatile("s_waitcnt vmcnt(0)" ::: "memory");  // publish before total
    }
    __hip_atomic_fetch_add(&ctl[CT_TOTAL], 1u, __ATOMIC_RELAXED,
                           __HIP_MEMORY_SCOPE_AGENT);
    unsigned m;
    for (;;) {
      m = __hip_atomic_load(&ctl[CT_MAP + slot], __ATOMIC_RELAXED,
                            __HIP_MEMORY_SCOPE_AGENT);
      if (m) break;
      if (__hip_atomic_load(&ctl[CT_TOTAL], __ATOMIC_RELAXED,
                            __HIP_MEMORY_SCOPE_AGENT) >= (unsigned)NLAUNCH) {
        m = __hip_atomic_load(&ctl[CT_MAP + slot], __ATOMIC_RELAXED,
                              __HIP_MEMORY_SCOPE_AGENT);
        break;
      }
      __builtin_amdgcn_s_sleep(2);
    }
    role[0] = (m == 0 || m > (unsigned)G) ? -1 : (int)(m - 1);
    role[1] = (int)(rank & 15u);
  }
  __syncthreads();
  if (role[0] < 0) return;   // surplus / incomplete cohort: exit
  const int g = role[0];     // group id 0..3  (samples [g*32, g*32+32))
  const int j = role[1];     // 32-col weight shard 0..15

  const int wave = tid >> 6;
  const int lane = tid & 63;
  const int n = lane & 15;
  const int kq = lane >> 4;
  const int ct = wave & 1;         // col-tile within shard
  const int rt = wave >> 1;        // row-tile (samples)
  const int colt = j * 2 + ct;     // global 16-col tile
  const int sl2 = rt * 16 + n;     // this lane's sample (D col = lane&15)
  const int gc0 = j * 32 + ct * 16 + kq * 4;  // lane's 4-col base (D rows)
  const int s0 = g * S;

  // ---- weights into registers (272 VGPRs of frags) ----
  bf16x8_t w1f[16], whhf[16], w12f[16], whh2f[16], wihf[4];
#pragma unroll
  for (int kt = 0; kt < 16; ++kt) {
    w1f[kt]   = ld_frag(W1p   + (size_t)(colt * 16 + kt) * 512 + lane * 8);
    whhf[kt]  = ld_frag(Whhp  + (size_t)(colt * 16 + kt) * 512 + lane * 8);
    w12f[kt]  = ld_frag(W12p  + (size_t)(colt * 16 + kt) * 512 + lane * 8);
    whh2f[kt] = ld_frag(Whh2p + (size_t)(colt * 16 + kt) * 512 + lane * 8);
  }
#pragma unroll
  for (int kt = 0; kt < 4; ++kt)
    wihf[kt] = ld_frag(Wihp + (size_t)(colt * 4 + kt) * 512 + lane * 8);

  const f32x4_t b1v = *reinterpret_cast<const f32x4_t*>(&b1[gc0]);
  const f32x4_t c1v = *reinterpret_cast<const f32x4_t*>(&c1[gc0]);
  const f32x4_t cwv = *reinterpret_cast<const f32x4_t*>(&cw[gc0]);
  f32x4_t bbv;
#pragma unroll
  for (int r_ = 0; r_ < 4; ++r_) bbv[r_] = bih[gc0 + r_] + bhh[gc0 + r_];
  f32x4_t fsv = {0.f, 0.f, 0.f, 0.f};  // sum of post-RNN h (lane-private)

  unsigned short* const myact = actg + (size_t)g * (2 * S * 512);
  unsigned int* const pf = &ctl[CT_PFLAG + g * 64];  // 16 words, own 256B
  int bar = 0;

  // Producer store offset (elems) in consumer B-frag order (R9-proven).
  const size_t soff =
      ((size_t)(rt * 16 + j) * 64 + n + 16 * (2 * ct + (kq >> 1))) * 8 +
      (kq & 1) * 4;
  const int row0 = rt * 16;

  asm volatile("buffer_inv" ::: "memory");   // drop any pre-kernel L1 lines
  asm volatile("s_waitcnt vmcnt(0)" ::: "memory");

  // signal (R9-verbatim): all waves drain own stores to local L2, block
  // barrier, tid0 plain volatile flag store.
  auto signal = [&]() {
    asm volatile("s_waitcnt vmcnt(0)" ::: "memory");
    __syncthreads();
    if (tid == 0)
      *(volatile unsigned int*)(pf + j) = (unsigned)(bar + 1);
  };
  // wait (R9-verbatim): poll 16 block-flags, buffer_inv each iter; the final
  // inv precedes the subsequent frag loads (no stale L1).
  auto wait_ = [&]() {
    const unsigned want = (unsigned)(bar + 1);
    for (;;) {
      asm volatile("buffer_inv" ::: "memory");
      unsigned v = *(volatile const unsigned int*)(pf + (lane & 15));
      if (__ballot(v < want) == 0ull) break;
    }
    ++bar;
  };

  // x @ Wih^T for f=0 (deferred slot computes f+1 thereafter)
  f32x4_t accx = {0.f, 0.f, 0.f, 0.f};
  {
    const ushort8_t* xsrc =
        (const ushort8_t*)xf + (size_t)((0 * 8 + g * 2 + rt) * 4) * 64;
#pragma unroll
    for (int kt = 0; kt < 4; ++kt) {
      bf16x8_t a = __builtin_bit_cast(bf16x8_t, xsrc[kt * 64 + lane]);
      accx = __builtin_amdgcn_mfma_f32_16x16x32_bf16(wihf[kt], a, accx, 0, 0, 0);
    }
  }

#pragma unroll 1
  for (int f = 0; f < FF; ++f) {
    const float dscale = dtp[f * 128 + s0 + sl2];  // lane-private dt
    f32x4_t z1, u, w1a;

    // ---- S1: xchg h -> z1 = h@W1^T + b1; publish g1=relu(z1);
    //          deferred: u = h@Whh^T (same frag regs) ----
    {
      const ushort8_t* src =
          (const ushort8_t*)(myact + (size_t)((bar & 1) ^ 1) * (S * 512));
      bf16x8_t a[16];
      ld16(src, row0, lane, a);
      f32x4_t acc = {0.f, 0.f, 0.f, 0.f};
      acc = mm16r(w1f, a, acc);
      unsigned short* dst = myact + (size_t)(bar & 1) * (S * 512);
      ushort4_t o;
#pragma unroll
      for (int r_ = 0; r_ < 4; ++r_) {
        z1[r_] = acc[r_] + b1v[r_];
        float y = z1[r_] > 0.f ? z1[r_] : 0.f;
        o[r_] = f2b(y);
      }
      *reinterpret_cast<ushort4_t*>(dst + soff) = o;
      signal();
      f32x4_t au = {0.f, 0.f, 0.f, 0.f};
      u = mm16r(whhf, a, au);
      wait_();
    }
    // ---- S2: xchg g1 -> z2 = z1 + 0.8dt(g1@W12^T + c1); publish relu(z2);
    //          deferred: w1 = g1@Whh2^T ----
    {
      const ushort8_t* src =
          (const ushort8_t*)(myact + (size_t)((bar & 1) ^ 1) * (S * 512));
      bf16x8_t a[16];
      ld16(src, row0, lane, a);
      f32x4_t acc = {0.f, 0.f, 0.f, 0.f};
      acc = mm16r(w12f, a, acc);
      unsigned short* dst = myact + (size_t)(bar & 1) * (S * 512);
      ushort4_t o;
#pragma unroll
      for (int r_ = 0; r_ < 4; ++r_) {
        float z2 = z1[r_] + 0.8f * dscale * (acc[r_] + c1v[r_]);
        float y = z2 > 0.f ? z2 : 0.f;
        o[r_] = f2b(y);
      }
      *reinterpret_cast<ushort4_t*>(dst + soff) = o;
      signal();
      f32x4_t aw = {0.f, 0.f, 0.f, 0.f};
      w1a = mm16r(whh2f, a, aw);
      wait_();
    }
    // ---- S3: xchg g2 -> w2 = g2@Whh2^T;
    //          h' = tanh(x@Wih^T + u + 0.5dt(w1+w2) + dt*cw + bb);
    //          publish h'; deferred: x@Wih^T for f+1 ----
    {
      const ushort8_t* src =
          (const ushort8_t*)(myact + (size_t)((bar & 1) ^ 1) * (S * 512));
      bf16x8_t a[16];
      ld16(src, row0, lane, a);
      f32x4_t acc = {0.f, 0.f, 0.f, 0.f};
      acc = mm16r(whh2f, a, acc);
      unsigned short* dst = myact + (size_t)(bar & 1) * (S * 512);
      ushort4_t o;
#pragma unroll
      for (int r_ = 0; r_ < 4; ++r_) {
        float pre = accx[r_] + u[r_] + 0.5f * dscale * (w1a[r_] + acc[r_]) +
                    dscale * cwv[r_] + bbv[r_];
        float t = tanhf(pre);
        fsv[r_] += t;
        o[r_] = f2b(t);
      }
      *reinterpret_cast<ushort4_t*>(dst + soff) = o;
      signal();
      accx = (f32x4_t){0.f, 0.f, 0.f, 0.f};
      if (f + 1 < FF) {
        const ushort8_t* xsrc =
            (const ushort8_t*)xf + (size_t)(((f + 1) * 8 + g * 2 + rt) * 4) * 64;
#pragma unroll
        for (int kt = 0; kt < 4; ++kt) {
          bf16x8_t ax = __builtin_bit_cast(bf16x8_t, xsrc[kt * 64 + lane]);
          accx = __builtin_amdgcn_mfma_f32_16x16x32_bf16(wihf[kt], ax, accx,
                                                         0, 0, 0);
        }
      }
      wait_();
    }
  }

  // ---- classifier: logits[s] += sum over this block's 32 cols ----
  {
    float p = fsv[0] * Wc[gc0] + fsv[1] * Wc[gc0 + 1] +
              fsv[2] * Wc[gc0 + 2] + fsv[3] * Wc[gc0 + 3];
    p += __shfl_xor(p, 16, 64);   // reduce over kq
    p += __shfl_xor(p, 32, 64);
    if (lane < 16) redl[rt * 16 + lane][ct] = p;
  }
  __syncthreads();
  if (tid < S) {
    float v = redl[tid][0] + redl[tid][1];
    atomicAdd(&logits[s0 + tid], v);   // device-scope, cross-XCD safe
  }
}

__global__ void fin_kernel(const float* __restrict__ logits,
                           const float* __restrict__ bc,
                           float* __restrict__ out) {
  int b = threadIdx.x;
  if (b < 128) out[b] = 1.f / (1.f + __expf(-(logits[b] * (1.f / FF) + bc[0])));
}

// --- launch -----------------------------------------------------------------
extern "C" void kernel_launch(void* const* d_in, const int* in_sizes, int n_in,
                              void* d_out, int out_size, void* d_ws, size_t ws_size,
                              hipStream_t stream) {
  const float* x   = (const float*)d_in[0];
  const float* tp  = (const float*)d_in[1];
  const float* W1  = (const float*)d_in[2];
  const float* b1  = (const float*)d_in[3];
  const float* W2  = (const float*)d_in[4];
  const float* b2  = (const float*)d_in[5];
  const float* Wih = (const float*)d_in[6];
  const float* Whh = (const float*)d_in[7];
  const float* bih = (const float*)d_in[8];
  const float* bhh = (const float*)d_in[9];
  const float* Wc  = (const float*)d_in[10];
  const float* bc  = (const float*)d_in[11];
  float* out = (float*)d_out;

  unsigned short* W1p   = (unsigned short*)d_ws;
  unsigned short* Whhp  = W1p + (size_t)HD * HD;
  unsigned short* W12p  = Whhp + (size_t)HD * HD;
  unsigned short* Whh2p = W12p + (size_t)HD * HD;
  unsigned short* Wihp  = Whh2p + (size_t)HD * HD;
  unsigned short* xfp   = Wihp + (size_t)HD * ID;
  float*          dtp   = (float*)(xfp + XFRAG_ELEMS);
  float*          c1    = dtp + FF * 128;
  float*          cwv   = c1 + HD;
  float*          W12t  = cwv + HD;                 // fp32 temp 1MB
  float*          Whh2t = W12t + (size_t)HD * HD;   // fp32 temp 1MB
  unsigned short* actg  = (unsigned short*)(Whh2t + (size_t)HD * HD);
  unsigned int*   ctl   = (unsigned int*)(actg + (size_t)G * 2 * S * 512);
  float*          logits = (float*)(ctl + CT_WORDS);
  // total ws use ~21.6 MB

  // precompute W12 = W1*W2, Whh2 = Whh*W2, c1 = W1*b2, cw = Whh*b2
  mm512_kernel<<<512, 256, 0, stream>>>(W1, W2, W12t);
  mm512_kernel<<<512, 256, 0, stream>>>(Whh, W2, Whh2t);
  mv_kernel<<<2, 256, 0, stream>>>(W1, b2, c1);
  mv_kernel<<<2, 256, 0, stream>>>(Whh, b2, cwv);

  pack_kernel<<<(HD * HD + 255) / 256, 256, 0, stream>>>(W1, W1p, HD);
  pack_kernel<<<(HD * HD + 255) / 256, 256, 0, stream>>>(Whh, Whhp, HD);
  pack_kernel<<<(HD * HD + 255) / 256, 256, 0, stream>>>(W12t, W12p, HD);
  pack_kernel<<<(HD * HD + 255) / 256, 256, 0, stream>>>(Whh2t, Whh2p, HD);
  pack_kernel<<<(HD * ID + 255) / 256, 256, 0, stream>>>(Wih, Wihp, ID);
  xpack_kernel<<<(int)((XFRAG_ELEMS + 255) / 256), 256, 0, stream>>>(x, xfp);
  dtpack_kernel<<<(FF * 128 + 255) / 256, 256, 0, stream>>>(tp, dtp);
  // zero actg (h0 = 0 read at f=0, both parities) + ctl + logits (contiguous)
  int nz = (int)(G * 2 * S * 512 / 2) + CT_WORDS + 128;
  zero_kernel<<<(nz + 255) / 256, 256, 0, stream>>>((unsigned int*)actg, nz);

  seq_kernel<<<dim3(NLAUNCH), dim3(256), 0, stream>>>(
      dtp, b1, c1, cwv, bih, bhh, Wc, W1p, Whhp, W12p, Whh2p, Wihp, xfp,
      actg, ctl, logits);
  fin_kernel<<<dim3(1), dim3(128), 0, stream>>>(logits, bc, out);
}